// Round 2
// baseline (672.513 us; speedup 1.0000x reference)
//
#include <hip/hip_runtime.h>

// CompressiveMemory.update() — B=65536, R=K=8, D=256, fp32.
// One wave (64 lanes) per sample; 4 samples per 256-thread block.
// Branches (insert / shift / passthrough) are wave-uniform.
// valid_mask is a numpy bool -> harness pushes as int32 ("integer -> const int*").

#define NB 65536
#define RR 8
#define KK 8
#define DD 256

__global__ __launch_bounds__(256) void cm_update_kernel(
    const float* __restrict__ fm,          // (B,R,D)
    const float* __restrict__ cm,          // (B,K,D)
    const int* __restrict__ cnt_in,        // (B,)
    const float* __restrict__ seg,         // (B,D)
    const int* __restrict__ valid,         // (B,) bool widened to int32
    const float* __restrict__ W,           // (D,D,2)
    const float* __restrict__ bias,        // (D,)
    float* __restrict__ out_fm,            // (B,R,D)
    float* __restrict__ out_cm,            // (B,K,D)
    float* __restrict__ out_cnt)           // (B,) as float
{
    const int wave = threadIdx.x >> 6;
    const int lane = threadIdx.x & 63;
    const int b = (blockIdx.x << 2) + wave;   // grid = NB/4 blocks

    const int cnt = cnt_in[b];
    const bool v   = valid[b] != 0;
    const bool ins = v && (cnt < RR);
    const bool shf = v && (cnt >= RR);

    const float* fmb  = fm  + (size_t)b * (RR * DD);
    const float* cmb  = cm  + (size_t)b * (KK * DD);
    const float* segb = seg + (size_t)b * DD;
    float* ofm = out_fm + (size_t)b * (RR * DD);
    float* ocm = out_cm + (size_t)b * (KK * DD);

    const int c = lane << 2;   // 4 columns per lane, 64 lanes * 4 = 256 = D

    if (shf) {
        // c_new[o] = sum_i cm_last[i]*W[o,i,0] + fm0[i]*W[o,i,1] + bias[o]
        // lane owns o = c..c+3; W row o is 512 contiguous floats (i,k) pairs.
        float acc0 = bias[c + 0];
        float acc1 = bias[c + 1];
        float acc2 = bias[c + 2];
        float acc3 = bias[c + 3];
        const float* xc = cmb + (KK - 1) * DD;   // cm last row
        const float* xf = fmb;                   // fm first row
        const float* w0 = W + (size_t)(c + 0) * (DD * 2);
        const float* w1 = W + (size_t)(c + 1) * (DD * 2);
        const float* w2 = W + (size_t)(c + 2) * (DD * 2);
        const float* w3 = W + (size_t)(c + 3) * (DD * 2);
        #pragma unroll 4
        for (int i = 0; i < DD; i += 2) {
            // x-vectors are wave-uniform -> scalar/broadcast loads from cache
            const float2 a = *(const float2*)(xc + i);
            const float2 f = *(const float2*)(xf + i);
            const float4 q0 = *(const float4*)(w0 + i * 2);
            const float4 q1 = *(const float4*)(w1 + i * 2);
            const float4 q2 = *(const float4*)(w2 + i * 2);
            const float4 q3 = *(const float4*)(w3 + i * 2);
            acc0 += a.x * q0.x + f.x * q0.y + a.y * q0.z + f.y * q0.w;
            acc1 += a.x * q1.x + f.x * q1.y + a.y * q1.z + f.y * q1.w;
            acc2 += a.x * q2.x + f.x * q2.y + a.y * q2.z + f.y * q2.w;
            acc3 += a.x * q3.x + f.x * q3.y + a.y * q3.z + f.y * q3.w;
        }
        // fm: shift left, append new_segment
        #pragma unroll
        for (int r = 0; r < RR - 1; ++r)
            *(float4*)(ofm + r * DD + c) = *(const float4*)(fmb + (r + 1) * DD + c);
        *(float4*)(ofm + (RR - 1) * DD + c) = *(const float4*)(segb + c);
        // cm: shift left, append c_new
        #pragma unroll
        for (int k = 0; k < KK - 1; ++k)
            *(float4*)(ocm + k * DD + c) = *(const float4*)(cmb + (k + 1) * DD + c);
        *(float4*)(ocm + (KK - 1) * DD + c) = make_float4(acc0, acc1, acc2, acc3);
    } else {
        float4 sv = make_float4(0.f, 0.f, 0.f, 0.f);
        if (ins) sv = *(const float4*)(segb + c);   // wave-uniform branch
        #pragma unroll
        for (int r = 0; r < RR; ++r) {
            float4 x = *(const float4*)(fmb + r * DD + c);
            if (ins && r == cnt) x = sv;
            *(float4*)(ofm + r * DD + c) = x;
        }
        #pragma unroll
        for (int k = 0; k < KK; ++k)
            *(float4*)(ocm + k * DD + c) = *(const float4*)(cmb + k * DD + c);
    }

    if (lane == 0)
        out_cnt[b] = (float)(cnt + (ins ? 1 : 0));
}

extern "C" void kernel_launch(void* const* d_in, const int* in_sizes, int n_in,
                              void* d_out, int out_size, void* d_ws, size_t ws_size,
                              hipStream_t stream) {
    const float* fm    = (const float*)d_in[0];
    const float* cm    = (const float*)d_in[1];
    const int*   cnt   = (const int*)d_in[2];
    const float* seg   = (const float*)d_in[3];
    const int*   valid = (const int*)d_in[4];
    const float* W     = (const float*)d_in[5];
    const float* bias  = (const float*)d_in[6];

    float* out_fm  = (float*)d_out;
    float* out_cm  = out_fm + (size_t)NB * RR * DD;
    float* out_cnt = out_cm + (size_t)NB * KK * DD;

    dim3 grid(NB / 4), block(256);
    hipLaunchKernelGGL(cm_update_kernel, grid, block, 0, stream,
                       fm, cm, cnt, seg, valid, W, bias, out_fm, out_cm, out_cnt);
}

// Round 3
// 458.382 us; speedup vs baseline: 1.4671x; 1.4671x over previous
//
#include <hip/hip_runtime.h>

// CompressiveMemory.update() — B=65536, R=K=8, D=256, fp32.
// 3-kernel plan:
//   k0: transpose W (D,D,2) -> Wt (512, 256) in ws  [coalesced conv reads later]
//   k1: pure-streaming row copy, one wave per 256-float output row; wave-uniform
//       branch; compacts shift-samples into a ws list (1 atomic per sample).
//   k2: conv c_new for compacted samples only; 8 samples/wave, x staged in LDS,
//       Wt loads fully coalesced (1KB per wave-instr); writes out_cm row 7.

#define NB 65536
#define RR 8
#define KK 8
#define DD 256
#define WFLOATS (DD * DD * 2)   // 131072 floats = 512KB

// ws layout (bytes):
//   [0]          int counter
//   [64]         int list[NB]            (262144 B)
//   [64+262144]  float Wt[512][256]      (524288 B)
#define WS_LIST_OFF 64
#define WS_WT_OFF   (64 + NB * 4)

__global__ __launch_bounds__(256) void transpose_w(
    const float* __restrict__ W, float* __restrict__ Wt)
{
    int t = blockIdx.x * 256 + threadIdx.x;       // 0 .. 131071
    int o = t >> 9;                                // W row (out channel)
    int m = t & 511;                               // i*2+k within row
    Wt[m * DD + o] = W[t];                         // coalesced read, scattered write (512KB once)
}

__global__ __launch_bounds__(256) void stream_update(
    const float* __restrict__ fm,          // (B,R,D)
    const float* __restrict__ cm,          // (B,K,D)
    const int* __restrict__ cnt_in,        // (B,)
    const float* __restrict__ seg,         // (B,D)
    const int* __restrict__ valid,         // (B,) bool widened to int32
    float* __restrict__ out_fm,
    float* __restrict__ out_cm,
    float* __restrict__ out_cnt,           // (B,) as float
    int* __restrict__ counter,
    int* __restrict__ list)
{
    const int row  = blockIdx.x * 4 + (threadIdx.x >> 6);  // B*16 rows total
    const int lane = threadIdx.x & 63;
    const int b    = row >> 4;
    const int sub  = row & 15;
    const int c    = lane << 2;

    const int  cnt = cnt_in[b];
    const bool v   = valid[b] != 0;
    const bool ins = v && (cnt < RR);
    const bool shf = v && (cnt >= RR);

    if (sub < 8) {                                   // fm row `sub`
        const float* src;
        if (shf)      src = (sub < 7) ? fm + ((size_t)b * RR + sub + 1) * DD
                                      : seg + (size_t)b * DD;
        else if (ins && sub == cnt)
                      src = seg + (size_t)b * DD;
        else          src = fm + ((size_t)b * RR + sub) * DD;
        float4 x = *(const float4*)(src + c);
        *(float4*)(out_fm + ((size_t)b * RR + sub) * DD + c) = x;

        if (sub == 0 && lane == 0) {
            out_cnt[b] = (float)(cnt + (ins ? 1 : 0));
            if (shf) { int p = atomicAdd(counter, 1); list[p] = b; }
        }
    } else {                                         // cm row j
        const int j = sub - 8;
        if (shf) {
            if (j < 7) {                             // shift left; row 7 by conv kernel
                float4 x = *(const float4*)(cm + ((size_t)b * KK + j + 1) * DD + c);
                *(float4*)(out_cm + ((size_t)b * KK + j) * DD + c) = x;
            }
        } else {
            float4 x = *(const float4*)(cm + ((size_t)b * KK + j) * DD + c);
            *(float4*)(out_cm + ((size_t)b * KK + j) * DD + c) = x;
        }
    }
}

#define SPB 32   // samples per block
#define SPW 8    // samples per wave (4 waves)

__global__ __launch_bounds__(256) void conv_kernel(
    const float* __restrict__ fm,
    const float* __restrict__ cm,
    const float* __restrict__ Wt,          // (512, 256)
    const float* __restrict__ bias,        // (256,)
    float* __restrict__ out_cm,
    const int* __restrict__ counter,
    const int* __restrict__ list)
{
    __shared__ float xbuf[SPB][512];       // 64KB: interleaved [cm_last, fm0]
    const int count = *counter;
    const int base  = blockIdx.x * SPB;
    if (base >= count) return;

    const int wave = threadIdx.x >> 6;
    const int lane = threadIdx.x & 63;
    const int s0   = wave * SPW;

    int bs[SPW];
    #pragma unroll
    for (int s = 0; s < SPW; ++s) {
        const int idx = base + s0 + s;
        bs[s] = (idx < count) ? list[idx] : -1;
        if (bs[s] >= 0) {
            const float* cl = cm + ((size_t)bs[s] * KK + (KK - 1)) * DD;
            const float* f0 = fm + (size_t)bs[s] * RR * DD;
            float4 cv = *(const float4*)(cl + lane * 4);
            float4 fv = *(const float4*)(f0 + lane * 4);
            // xbuf[s][i*2+0]=cm_last[i], [i*2+1]=fm0[i]; lane covers i=lane*4..+3
            *(float4*)&xbuf[s0 + s][lane * 8]     = make_float4(cv.x, fv.x, cv.y, fv.y);
            *(float4*)&xbuf[s0 + s][lane * 8 + 4] = make_float4(cv.z, fv.z, cv.w, fv.w);
        }
    }
    // Each wave reads only its own xbuf rows -> no block barrier needed;
    // compiler inserts lgkmcnt for the within-wave write->read dependency.

    float acc[SPW][4];
    #pragma unroll
    for (int s = 0; s < SPW; ++s)
        acc[s][0] = acc[s][1] = acc[s][2] = acc[s][3] = 0.f;

    // c_new[o] = sum_m xbuf[s][m] * Wt[m][o],  lane owns o = lane*4 .. +3
    for (int m4 = 0; m4 < 128; ++m4) {
        const float4 w0 = *(const float4*)(Wt + (size_t)(m4 * 4 + 0) * DD + lane * 4);
        const float4 w1 = *(const float4*)(Wt + (size_t)(m4 * 4 + 1) * DD + lane * 4);
        const float4 w2 = *(const float4*)(Wt + (size_t)(m4 * 4 + 2) * DD + lane * 4);
        const float4 w3 = *(const float4*)(Wt + (size_t)(m4 * 4 + 3) * DD + lane * 4);
        #pragma unroll
        for (int s = 0; s < SPW; ++s) {
            const float4 xq = *(const float4*)&xbuf[s0 + s][m4 * 4];  // uniform -> broadcast
            acc[s][0] += xq.x * w0.x + xq.y * w1.x + xq.z * w2.x + xq.w * w3.x;
            acc[s][1] += xq.x * w0.y + xq.y * w1.y + xq.z * w2.y + xq.w * w3.y;
            acc[s][2] += xq.x * w0.z + xq.y * w1.z + xq.z * w2.z + xq.w * w3.z;
            acc[s][3] += xq.x * w0.w + xq.y * w1.w + xq.z * w2.w + xq.w * w3.w;
        }
    }

    const float4 bv = *(const float4*)(bias + lane * 4);
    #pragma unroll
    for (int s = 0; s < SPW; ++s) {
        if (bs[s] >= 0) {
            float4 r = make_float4(acc[s][0] + bv.x, acc[s][1] + bv.y,
                                   acc[s][2] + bv.z, acc[s][3] + bv.w);
            *(float4*)(out_cm + ((size_t)bs[s] * KK + (KK - 1)) * DD + lane * 4) = r;
        }
    }
}

extern "C" void kernel_launch(void* const* d_in, const int* in_sizes, int n_in,
                              void* d_out, int out_size, void* d_ws, size_t ws_size,
                              hipStream_t stream) {
    const float* fm    = (const float*)d_in[0];
    const float* cm    = (const float*)d_in[1];
    const int*   cnt   = (const int*)d_in[2];
    const float* seg   = (const float*)d_in[3];
    const int*   valid = (const int*)d_in[4];
    const float* W     = (const float*)d_in[5];
    const float* bias  = (const float*)d_in[6];

    float* out_fm  = (float*)d_out;
    float* out_cm  = out_fm + (size_t)NB * RR * DD;
    float* out_cnt = out_cm + (size_t)NB * KK * DD;

    int*   counter = (int*)d_ws;
    int*   list    = (int*)((char*)d_ws + WS_LIST_OFF);
    float* Wt      = (float*)((char*)d_ws + WS_WT_OFF);

    hipMemsetAsync(d_ws, 0, 64, stream);   // zero the compaction counter

    hipLaunchKernelGGL(transpose_w, dim3(WFLOATS / 256), dim3(256), 0, stream, W, Wt);
    hipLaunchKernelGGL(stream_update, dim3(NB * 16 / 4), dim3(256), 0, stream,
                       fm, cm, cnt, seg, valid, out_fm, out_cm, out_cnt, counter, list);
    hipLaunchKernelGGL(conv_kernel, dim3(NB / SPB), dim3(256), 0, stream,
                       fm, cm, Wt, bias, out_cm, counter, list);
}

// Round 4
// 434.659 us; speedup vs baseline: 1.5472x; 1.0546x over previous
//
#include <hip/hip_runtime.h>

// CompressiveMemory.update() — B=65536, R=K=8, D=256, fp32.
//   k0 transpose_w: W (D,D,2) -> Wt (512,256) in ws; also zeroes compaction counter.
//   k1 stream_update: 1 block per sample; wave w handles fm rows {w,w+4} and
//      cm rows {w,w+4} -> 4 independent nontemporal 1KB loads + 4 stores (MLP=4).
//      Shift-samples compacted into ws list (1 atomic per sample).
//   k2 conv_kernel: c_new for compacted samples; 8 samples/wave, x in LDS,
//      coalesced Wt loads; writes out_cm row 7.

#define NB 65536
#define RR 8
#define KK 8
#define DD 256
#define WFLOATS (DD * DD * 2)

#define WS_LIST_OFF 64
#define WS_WT_OFF   (64 + NB * 4)

typedef float f4 __attribute__((ext_vector_type(4)));

static __device__ __forceinline__ f4 ntload(const float* p) {
    return __builtin_nontemporal_load((const f4*)p);
}
static __device__ __forceinline__ void ntstore(float* p, f4 v) {
    __builtin_nontemporal_store(v, (f4*)p);
}

__global__ __launch_bounds__(256) void transpose_w(
    const float* __restrict__ W, float* __restrict__ Wt, int* __restrict__ counter)
{
    int t = blockIdx.x * 256 + threadIdx.x;
    if (t == 0) *counter = 0;
    int o = t >> 9;
    int m = t & 511;
    Wt[m * DD + o] = W[t];
}

__global__ __launch_bounds__(256) void stream_update(
    const float* __restrict__ fm,          // (B,R,D)
    const float* __restrict__ cm,          // (B,K,D)
    const int* __restrict__ cnt_in,
    const float* __restrict__ seg,         // (B,D)
    const int* __restrict__ valid,
    float* __restrict__ out_fm,
    float* __restrict__ out_cm,
    float* __restrict__ out_cnt,
    int* __restrict__ counter,
    int* __restrict__ list)
{
    const int b    = blockIdx.x;
    const int w    = threadIdx.x >> 6;     // 0..3
    const int lane = threadIdx.x & 63;
    const int c    = lane << 2;

    const int  cnt = cnt_in[b];
    const bool v   = valid[b] != 0;
    const bool ins = v && (cnt < RR);
    const bool shf = v && (cnt >= RR);

    const float* fmb  = fm  + (size_t)b * (RR * DD);
    const float* cmb  = cm  + (size_t)b * (KK * DD);
    const float* segb = seg + (size_t)b * DD;
    float* ofm = out_fm + (size_t)b * (RR * DD);
    float* ocm = out_cm + (size_t)b * (KK * DD);

    const int r0 = w, r1 = w + 4;

    // fm sources (wave-uniform selection)
    const float* f0src = shf ? fmb + (r0 + 1) * DD
                             : (ins && r0 == cnt) ? segb : fmb + r0 * DD;
    const float* f1src = shf ? ((r1 < 7) ? fmb + (r1 + 1) * DD : segb)
                             : (ins && r1 == cnt) ? segb : fmb + r1 * DD;
    // cm sources; shf && row==7 handled by conv kernel (skip)
    const bool   c1st  = !(shf && r1 == 7);
    const float* c0src = cmb + (shf ? r0 + 1 : r0) * DD;
    const float* c1src = c1st ? cmb + (shf ? r1 + 1 : r1) * DD : cmb;

    // issue all loads first (MLP=4)
    f4 a = ntload(f0src + c);
    f4 bq = ntload(f1src + c);
    f4 d = ntload(c0src + c);
    f4 e = ntload(c1src + c);

    ntstore(ofm + r0 * DD + c, a);
    ntstore(ofm + r1 * DD + c, bq);
    ntstore(ocm + r0 * DD + c, d);
    if (c1st) ntstore(ocm + r1 * DD + c, e);

    if (w == 0 && lane == 0) {
        out_cnt[b] = (float)(cnt + (ins ? 1 : 0));
        if (shf) { int p = atomicAdd(counter, 1); list[p] = b; }
    }
}

#define SPB 32
#define SPW 8

__global__ __launch_bounds__(256) void conv_kernel(
    const float* __restrict__ fm,
    const float* __restrict__ cm,
    const float* __restrict__ Wt,
    const float* __restrict__ bias,
    float* __restrict__ out_cm,
    const int* __restrict__ counter,
    const int* __restrict__ list)
{
    __shared__ float xbuf[SPB][512];
    const int count = *counter;
    const int base  = blockIdx.x * SPB;
    if (base >= count) return;

    const int wave = threadIdx.x >> 6;
    const int lane = threadIdx.x & 63;
    const int s0   = wave * SPW;

    int bs[SPW];
    #pragma unroll
    for (int s = 0; s < SPW; ++s) {
        const int idx = base + s0 + s;
        bs[s] = (idx < count) ? list[idx] : -1;
        if (bs[s] >= 0) {
            const float* cl = cm + ((size_t)bs[s] * KK + (KK - 1)) * DD;
            const float* f0 = fm + (size_t)bs[s] * RR * DD;
            float4 cv = *(const float4*)(cl + lane * 4);
            float4 fv = *(const float4*)(f0 + lane * 4);
            *(float4*)&xbuf[s0 + s][lane * 8]     = make_float4(cv.x, fv.x, cv.y, fv.y);
            *(float4*)&xbuf[s0 + s][lane * 8 + 4] = make_float4(cv.z, fv.z, cv.w, fv.w);
        }
    }

    float acc[SPW][4];
    #pragma unroll
    for (int s = 0; s < SPW; ++s)
        acc[s][0] = acc[s][1] = acc[s][2] = acc[s][3] = 0.f;

    for (int m4 = 0; m4 < 128; ++m4) {
        const float4 w0 = *(const float4*)(Wt + (size_t)(m4 * 4 + 0) * DD + lane * 4);
        const float4 w1 = *(const float4*)(Wt + (size_t)(m4 * 4 + 1) * DD + lane * 4);
        const float4 w2 = *(const float4*)(Wt + (size_t)(m4 * 4 + 2) * DD + lane * 4);
        const float4 w3 = *(const float4*)(Wt + (size_t)(m4 * 4 + 3) * DD + lane * 4);
        #pragma unroll
        for (int s = 0; s < SPW; ++s) {
            const float4 xq = *(const float4*)&xbuf[s0 + s][m4 * 4];
            acc[s][0] += xq.x * w0.x + xq.y * w1.x + xq.z * w2.x + xq.w * w3.x;
            acc[s][1] += xq.x * w0.y + xq.y * w1.y + xq.z * w2.y + xq.w * w3.y;
            acc[s][2] += xq.x * w0.z + xq.y * w1.z + xq.z * w2.z + xq.w * w3.z;
            acc[s][3] += xq.x * w0.w + xq.y * w1.w + xq.z * w2.w + xq.w * w3.w;
        }
    }

    const float4 bv = *(const float4*)(bias + lane * 4);
    #pragma unroll
    for (int s = 0; s < SPW; ++s) {
        if (bs[s] >= 0) {
            float4 r = make_float4(acc[s][0] + bv.x, acc[s][1] + bv.y,
                                   acc[s][2] + bv.z, acc[s][3] + bv.w);
            *(float4*)(out_cm + ((size_t)bs[s] * KK + (KK - 1)) * DD + lane * 4) = r;
        }
    }
}

extern "C" void kernel_launch(void* const* d_in, const int* in_sizes, int n_in,
                              void* d_out, int out_size, void* d_ws, size_t ws_size,
                              hipStream_t stream) {
    const float* fm    = (const float*)d_in[0];
    const float* cm    = (const float*)d_in[1];
    const int*   cnt   = (const int*)d_in[2];
    const float* seg   = (const float*)d_in[3];
    const int*   valid = (const int*)d_in[4];
    const float* W     = (const float*)d_in[5];
    const float* bias  = (const float*)d_in[6];

    float* out_fm  = (float*)d_out;
    float* out_cm  = out_fm + (size_t)NB * RR * DD;
    float* out_cnt = out_cm + (size_t)NB * KK * DD;

    int*   counter = (int*)d_ws;
    int*   list    = (int*)((char*)d_ws + WS_LIST_OFF);
    float* Wt      = (float*)((char*)d_ws + WS_WT_OFF);

    hipLaunchKernelGGL(transpose_w, dim3(WFLOATS / 256), dim3(256), 0, stream, W, Wt, counter);
    hipLaunchKernelGGL(stream_update, dim3(NB), dim3(256), 0, stream,
                       fm, cm, cnt, seg, valid, out_fm, out_cm, out_cnt, counter, list);
    hipLaunchKernelGGL(conv_kernel, dim3(NB / SPB), dim3(256), 0, stream,
                       fm, cm, Wt, bias, out_cm, counter, list);
}

// Round 5
// 417.424 us; speedup vs baseline: 1.6111x; 1.0413x over previous
//
#include <hip/hip_runtime.h>

// CompressiveMemory.update() — B=65536, R=K=8, D=256, fp32.
// 2-kernel plan:
//   k0 transpose_pack: W (o,i,k) -> Wt2[m4][o][j] (m=i*2+k, j=m&3, m4=m>>2),
//      512KB in ws. Gives each conv thread a coalesced float4 of its 4 m-taps.
//   k1 fused stream+conv: 1 block (256 thr) per sample. Branch is BLOCK-uniform
//      (depends only on blockIdx) -> shift blocks do the 2-tap conv inline:
//      stage x=[cm7,fm0] interleaved in LDS, 128 iters of 4KB coalesced Wt2
//      loads, write out_cm row 7. Conv overlaps other blocks' HBM streaming.

#define NB 65536
#define RR 8
#define KK 8
#define DD 256
#define WFLOATS (DD * DD * 2)

typedef float f4 __attribute__((ext_vector_type(4)));

static __device__ __forceinline__ f4 ntload(const float* p) {
    return __builtin_nontemporal_load((const f4*)p);
}
static __device__ __forceinline__ void ntstore(float* p, f4 v) {
    __builtin_nontemporal_store(v, (f4*)p);
}

__global__ __launch_bounds__(256) void transpose_pack(
    const float* __restrict__ W, float* __restrict__ Wt2)
{
    int t = blockIdx.x * 256 + threadIdx.x;   // 0..131071, coalesced read
    int o = t >> 9;
    int m = t & 511;                          // m = i*2 + k
    Wt2[(size_t)(m >> 2) * (DD * 4) + o * 4 + (m & 3)] = W[t];
}

__global__ __launch_bounds__(256) void fused_update(
    const float* __restrict__ fm,          // (B,R,D)
    const float* __restrict__ cm,          // (B,K,D)
    const int* __restrict__ cnt_in,
    const float* __restrict__ seg,         // (B,D)
    const int* __restrict__ valid,
    const float* __restrict__ Wt2,         // (128, 256, 4)
    const float* __restrict__ bias,        // (256,)
    float* __restrict__ out_fm,
    float* __restrict__ out_cm,
    float* __restrict__ out_cnt)
{
    __shared__ float xbuf[512];            // x[2i]=cm7[i], x[2i+1]=fm0[i]

    const int b    = blockIdx.x;
    const int tid  = threadIdx.x;
    const int w    = tid >> 6;             // 0..3
    const int lane = tid & 63;
    const int c    = lane << 2;

    const int  cnt = cnt_in[b];
    const bool v   = valid[b] != 0;
    const bool ins = v && (cnt < RR);
    const bool shf = v && (cnt >= RR);     // block-uniform

    const float* fmb  = fm  + (size_t)b * (RR * DD);
    const float* cmb  = cm  + (size_t)b * (KK * DD);
    const float* segb = seg + (size_t)b * DD;
    float* ofm = out_fm + (size_t)b * (RR * DD);
    float* ocm = out_cm + (size_t)b * (KK * DD);

    const int r0 = w, r1 = w + 4;

    // fm sources (wave-uniform selection)
    const float* f0src = shf ? fmb + (r0 + 1) * DD
                             : (ins && r0 == cnt) ? segb : fmb + r0 * DD;
    const float* f1src = shf ? ((r1 < 7) ? fmb + (r1 + 1) * DD : segb)
                             : (ins && r1 == cnt) ? segb : fmb + r1 * DD;
    // cm sources; shf && row==7 produced by inline conv below
    const bool   c1st  = !(shf && r1 == 7);
    const float* c0src = cmb + (shf ? r0 + 1 : r0) * DD;
    const float* c1src = c1st ? cmb + (shf ? r1 + 1 : r1) * DD : cmb;

    // issue all stream loads first (MLP=4)
    f4 a  = ntload(f0src + c);
    f4 bq = ntload(f1src + c);
    f4 d  = ntload(c0src + c);
    f4 e  = ntload(c1src + c);

    ntstore(ofm + r0 * DD + c, a);
    ntstore(ofm + r1 * DD + c, bq);
    ntstore(ocm + r0 * DD + c, d);
    if (c1st) ntstore(ocm + r1 * DD + c, e);

    if (tid == 0)
        out_cnt[b] = (float)(cnt + (ins ? 1 : 0));

    if (shf) {                              // block-uniform -> barrier is safe
        // stage x interleaved: xbuf[2t]=cm7[t], xbuf[2t+1]=fm0[t]
        const float cv = cmb[(KK - 1) * DD + tid];
        const float fv = fmb[tid];
        xbuf[tid * 2]     = cv;
        xbuf[tid * 2 + 1] = fv;
        __syncthreads();

        // c_new[o] = sum_m x[m] * Wt2[m>>2][o][m&3], o = tid
        float acc = 0.f;
        const float* wp = Wt2 + tid * 4;
        #pragma unroll 8
        for (int m4 = 0; m4 < 128; ++m4) {
            const f4 wq = *(const f4*)(wp + (size_t)m4 * (DD * 4));
            const f4 xq = *(const f4*)&xbuf[m4 * 4];   // uniform -> broadcast
            acc += xq.x * wq.x + xq.y * wq.y + xq.z * wq.z + xq.w * wq.w;
        }
        acc += bias[tid];
        ocm[(KK - 1) * DD + tid] = acc;     // 1KB coalesced block store
    }
}

extern "C" void kernel_launch(void* const* d_in, const int* in_sizes, int n_in,
                              void* d_out, int out_size, void* d_ws, size_t ws_size,
                              hipStream_t stream) {
    const float* fm    = (const float*)d_in[0];
    const float* cm    = (const float*)d_in[1];
    const int*   cnt   = (const int*)d_in[2];
    const float* seg   = (const float*)d_in[3];
    const int*   valid = (const int*)d_in[4];
    const float* W     = (const float*)d_in[5];
    const float* bias  = (const float*)d_in[6];

    float* out_fm  = (float*)d_out;
    float* out_cm  = out_fm + (size_t)NB * RR * DD;
    float* out_cnt = out_cm + (size_t)NB * KK * DD;

    float* Wt2 = (float*)d_ws;             // 512KB

    hipLaunchKernelGGL(transpose_pack, dim3(WFLOATS / 256), dim3(256), 0, stream, W, Wt2);
    hipLaunchKernelGGL(fused_update, dim3(NB), dim3(256), 0, stream,
                       fm, cm, cnt, seg, valid, Wt2, bias, out_fm, out_cm, out_cnt);
}